// Round 9
// baseline (518.654 us; speedup 1.0000x reference)
//
#include <hip/hip_runtime.h>
#include <cstdint>
#include <cstddef>

#define NB 256
#define NS 2500
#define NJ 24
#define DF 131

#define QSEG 4           // n segments for k2m (md interface)
#define TSEG 640         // k2m/kW TILE-partition segment size: 40 tiles of 16

#define KP 2528          // padded K (c) for MFMA, 79 steps of 32
#define XNROWS 2512      // 157 tiles of 16
#define LP 160           // padded l for score MFMA (5 k-steps of 32)
#define PAD 134          // kP2 LDS row stride in shorts (dword stride 67, odd)

using short8 = __attribute__((ext_vector_type(8))) short;
using f32x4  = __attribute__((ext_vector_type(4))) float;

// ---- FULL-path ws byte offsets ----
#define F_XT   0ull                        // [NB][144][KP] bf16
#define F_XN   186384384ull                // [NB][XNROWS][LP] bf16
#define F_W1B  392167424ull                // [32][KP] bf16
#define F_QBF  392329216ull                // [NB][32][LP] bf16
#define F_H    394950656ull                // [NB][NJ][DF] f32
#define F_MD   398170112ull                // [NB][QSEG][48] f32
#define F_P    398366720ull                // [NB][NJ][KP] bf16
#define WS_FULL 429430784ull

__device__ __forceinline__ unsigned short f2bf(float x) {
  union { float f; unsigned u; } v; v.f = x;
  unsigned r = v.u + 0x7fffu + ((v.u >> 16) & 1u);   // RNE
  return (unsigned short)(r >> 16);
}
__device__ __forceinline__ float bf2f(unsigned us) {
  union { unsigned u; float f; } v; v.u = us << 16;
  return v.f;
}
__device__ __forceinline__ f32x4 mfma16(short8 a, short8 b, f32x4 c) {
  return __builtin_amdgcn_mfma_f32_16x16x32_bf16(a, b, c, 0, 0, 0);
}

// W1 [24][2500] f32 -> W1b [32][KP] bf16, zero-padded
__global__ __launch_bounds__(256) void kT2(const float* __restrict__ W1,
                                           unsigned short* __restrict__ W1b) {
  int dwi = blockIdx.x * 256 + threadIdx.x;
  if (dwi >= 32 * (KP / 2)) return;
  int row = dwi / (KP / 2);
  int kk = (dwi - row * (KP / 2)) * 2;
  unsigned lo = (row < NJ && kk     < NS) ? f2bf(W1[row * NS + kk])     : 0;
  unsigned hi = (row < NJ && kk + 1 < NS) ? f2bf(W1[row * NS + kk + 1]) : 0;
  ((unsigned*)W1b)[dwi] = lo | (hi << 16);
}

// X f32 [b][c][l] -> Xt bf16 [b][l][c-pad] + Xn bf16 [b][c][l-pad].
// LDS pad 134: 2a reads 2-way (free), 2b dword reads conflict-free (3r+lane)%32.
__global__ __launch_bounds__(256) void kP2(const float* __restrict__ sf,
                                           unsigned short* __restrict__ Xt,
                                           unsigned short* __restrict__ Xn) {
  __shared__ unsigned short xs[128 * PAD];         // 34304 B
  int b = blockIdx.x / 20;
  int chunk = blockIdx.x - 20 * b;
  int c0 = chunk * 128;
  int w = threadIdx.x >> 6, lane = threadIdx.x & 63;
  const float* xb = sf + (size_t)b * (NS * DF);

  // phase 1: coalesced f32 row reads, convert, u16 LDS stores (l=lane layout)
  for (int i = 0; i < 32; ++i) {
    int r = w * 32 + i;
    int c = c0 + r;
    bool vc = c < NS;
    const float* g = xb + (size_t)c * DF;
    float v0 = vc ? g[lane] : 0.f;
    float v1 = vc ? g[64 + lane] : 0.f;
    xs[r * PAD + lane] = f2bf(v0);
    xs[r * PAD + 64 + lane] = f2bf(v1);
    if (lane < 6)                                   // l 128..133: data + zero pad
      xs[r * PAD + 128 + lane] =
          (vc && lane < 3) ? f2bf(g[128 + lane]) : (unsigned short)0;
  }
  __syncthreads();

  // phase 2a: Xt[l][cc,cc+1] dword stores (lane-contiguous)
  int cc = c0 + 2 * lane;
  if (cc < KP) {
    unsigned short* xtb = Xt + (size_t)b * (144 * KP);
    for (int l = w; l < DF; l += 4) {
      unsigned lo = xs[(2 * lane) * PAD + l];       // banks (6*lane + l/2)%32: 2-way
      unsigned hi = xs[(2 * lane + 1) * PAD + l];
      *(unsigned*)(xtb + (size_t)l * KP + cc) = lo | (hi << 16);
    }
  }
  // phase 2b: Xn rows, dword-coalesced stores; LDS dword reads conflict-free
  if (Xn) {
    unsigned* xnb = (unsigned*)(Xn + (size_t)b * (XNROWS * LP));
    const unsigned* xsd = (const unsigned*)xs;
    for (int i = 0; i < 32; ++i) {
      int r = w * 32 + i;
      int c = c0 + r;
      if (c < XNROWS) {
        xnb[(size_t)c * (LP / 2) + lane] = xsd[67 * r + lane];   // l=2lane,2lane+1
        if (lane < 16) {                           // dwords 64..79 = l 128..159
          unsigned v = 0;
          if (lane < 2) v = xsd[67 * r + 64 + lane];  // (128,129) / (130,0-pad)
          xnb[(size_t)c * (LP / 2) + 64 + lane] = v;
        }
      }
    }
  }
}

// h[b][j][l] = (W1 @ X_b) via MFMA
__global__ __launch_bounds__(384) void kH(const unsigned short* __restrict__ Xt,
                                          const unsigned short* __restrict__ W1b,
                                          float* __restrict__ h) {
  int bi = blockIdx.x;
  int b = bi / 3, ng = bi - 3 * b;
  int wid = threadIdx.x >> 6, lane = threadIdx.x & 63;
  int m = wid / 3, nt = wid - 3 * m;
  int col0 = ng * 48 + nt * 16;
  int lr = lane & 15, lg = lane >> 4;

  const unsigned short* ap = W1b + (size_t)(m * 16 + lr) * KP + lg * 8;
  const unsigned short* bp = Xt + (size_t)b * (144 * KP) + (size_t)(col0 + lr) * KP + lg * 8;

  f32x4 acc = {0.f, 0.f, 0.f, 0.f};
#pragma unroll 4
  for (int ks = 0; ks < KP / 32; ++ks) {
    short8 av = *(const short8*)(ap + ks * 32);
    short8 bv = *(const short8*)(bp + ks * 32);
    acc = mfma16(av, bv, acc);
  }
  int lcol = col0 + lr;
  if (lcol < DF) {
    int jb = m * 16 + lg * 4;
#pragma unroll
    for (int r = 0; r < 4; ++r) {
      int j = jb + r;
      if (j < NJ) h[(size_t)b * (NJ * DF) + (size_t)j * DF + lcol] = acc[r];
    }
  }
}

// relu(h+b1) -> q = W2@. + b2 -> qbf bf16 [b][32][LP]
__global__ __launch_bounds__(512) void k1b(const float* __restrict__ h,
                                           const float* __restrict__ W2,
                                           const float* __restrict__ b1v,
                                           const float* __restrict__ b2v,
                                           unsigned short* __restrict__ qbf) {
  int flat = blockIdx.x * 512 + threadIdx.x;      // NB*LP threads
  if (flat >= NB * LP) return;
  int l = flat % LP;
  int b = flat / LP;
  unsigned short* qp = qbf + (size_t)b * (32 * LP) + l;
  if (l >= DF) {
#pragma unroll
    for (int j = 0; j < 32; ++j) qp[j * LP] = 0;
    return;
  }
  const float* p0 = h + (size_t)b * (NJ * DF) + l;
  float hv[NJ];
#pragma unroll
  for (int o = 0; o < NJ; ++o) hv[o] = fmaxf(b1v[o] + p0[o * DF], 0.f);
  float q[NJ];
  for (int o = 0; o < NJ; ++o) {
    float sv = b2v[o];
#pragma unroll
    for (int i = 0; i < NJ; ++i) sv = fmaf(W2[o * NJ + i], hv[i], sv);
    q[o] = sv;
  }
#pragma unroll
  for (int j = 0; j < NJ; ++j) qp[j * LP] = f2bf(q[j]);
#pragma unroll
  for (int j = NJ; j < 32; ++j) qp[j * LP] = 0;
}

// MFMA scores from Xn (bf16, 16B-aligned short8 loads), two-pass-in-registers:
// P = exp(S - m_seg) bf16 + per-seg (m,d). n partition BY TILES: seg = n/640.
__global__ __launch_bounds__(512) void k2m(const unsigned short* __restrict__ Xn,
                                           const unsigned short* __restrict__ qbf,
                                           unsigned short* __restrict__ P,
                                           float* __restrict__ md) {
  __shared__ float wm[8][24];
  __shared__ float wd[8][24];
  int b = blockIdx.x >> 2, seg = blockIdx.x & 3;
  int w = threadIdx.x >> 6, lane = threadIdx.x & 63;
  int lr = lane & 15, lg = lane >> 4;

  const unsigned short* qb = qbf + (size_t)b * (32 * LP);
  short8 aq0[5], aq1[5];
#pragma unroll
  for (int ks = 0; ks < 5; ++ks) {
    aq0[ks] = *(const short8*)(qb + (size_t)lr * LP + ks * 32 + lg * 8);
    aq1[ks] = *(const short8*)(qb + (size_t)(16 + lr) * LP + ks * 32 + lg * 8);
  }
  const unsigned short* xb = Xn + (size_t)b * (XNROWS * LP);
  int ntl = (seg < 3) ? 40 : 37;

  f32x4 s0[5], s1[5];
  float m8[8];
#pragma unroll
  for (int r = 0; r < 8; ++r) m8[r] = -1e30f;

#pragma unroll
  for (int i = 0; i < 5; ++i) {
    s0[i] = (f32x4){0.f, 0.f, 0.f, 0.f};
    s1[i] = (f32x4){0.f, 0.f, 0.f, 0.f};
    int ti = w + 8 * i;
    if (ti < ntl) {
      int n = (seg * 40 + ti) * 16 + lr;
      const unsigned short* bp = xb + (size_t)n * LP + lg * 8;
      short8 bx[5];
#pragma unroll
      for (int ks = 0; ks < 5; ++ks) bx[ks] = *(const short8*)(bp + ks * 32);
      f32x4 a0 = {0.f, 0.f, 0.f, 0.f}, a1 = {0.f, 0.f, 0.f, 0.f};
#pragma unroll
      for (int ks = 0; ks < 5; ++ks) {
        a0 = mfma16(aq0[ks], bx[ks], a0);
        a1 = mfma16(aq1[ks], bx[ks], a1);
      }
      s0[i] = a0; s1[i] = a1;
#pragma unroll
      for (int r = 0; r < 4; ++r) {
        m8[r]     = fmaxf(m8[r],     a0[r]);
        m8[4 + r] = fmaxf(m8[4 + r], a1[r]);
      }
    }
  }
  // max over 16 n-lanes
#pragma unroll
  for (int r = 0; r < 8; ++r)
#pragma unroll
    for (int off = 1; off < 16; off <<= 1)
      m8[r] = fmaxf(m8[r], __shfl_xor(m8[r], off));
  if (lr == 0) {
#pragma unroll
    for (int r = 0; r < 4; ++r) {
      wm[w][lg * 4 + r] = m8[r];
      if (lg < 2) wm[w][16 + lg * 4 + r] = m8[4 + r];
    }
  }
  __syncthreads();
  float mseg[8];
#pragma unroll
  for (int r = 0; r < 4; ++r) {
    float m0 = wm[0][lg * 4 + r];
#pragma unroll
    for (int wv = 1; wv < 8; ++wv) m0 = fmaxf(m0, wm[wv][lg * 4 + r]);
    mseg[r] = m0;
    int j1 = 16 + (lg & 1) * 4 + r;
    float m1 = wm[0][j1];
#pragma unroll
    for (int wv = 1; wv < 8; ++wv) m1 = fmaxf(m1, wm[wv][j1]);
    mseg[4 + r] = m1;
  }
  float d8[8];
#pragma unroll
  for (int r = 0; r < 8; ++r) d8[r] = 0.f;
#pragma unroll
  for (int i = 0; i < 5; ++i) {
    int ti = w + 8 * i;
    if (ti < ntl) {
      int n = (seg * 40 + ti) * 16 + lr;
      bool valid = n < NS;
#pragma unroll
      for (int r = 0; r < 4; ++r) {
        float p0 = __expf(s0[i][r] - mseg[r]);
        float p1 = __expf(s1[i][r] - mseg[4 + r]);
        if (valid) {
          P[((size_t)b * NJ + lg * 4 + r) * KP + n] = f2bf(p0);
          d8[r] += p0;
          if (lg < 2) {
            P[((size_t)b * NJ + 16 + lg * 4 + r) * KP + n] = f2bf(p1);
            d8[4 + r] += p1;
          }
        }
      }
    }
  }
#pragma unroll
  for (int r = 0; r < 8; ++r)
#pragma unroll
    for (int off = 1; off < 16; off <<= 1)
      d8[r] += __shfl_xor(d8[r], off);
  if (lr == 0) {
#pragma unroll
    for (int r = 0; r < 4; ++r) {
      wd[w][lg * 4 + r] = d8[r];
      if (lg < 2) wd[w][16 + lg * 4 + r] = d8[4 + r];
    }
  }
  __syncthreads();
  if (threadIdx.x < NJ) {
    int j = threadIdx.x;
    float m = wm[0][j], d = 0.f;
#pragma unroll
    for (int wv = 1; wv < 8; ++wv) m = fmaxf(m, wm[wv][j]);
#pragma unroll
    for (int wv = 0; wv < 8; ++wv) d += wd[wv][j];
    float* mp = md + ((size_t)b * QSEG + seg) * 48;
    mp[j] = m;
    mp[24 + j] = d;
  }
}

// combine md; write attention f32 (required output) + normalize P bf16 in place.
// Segment of n is the TILE partition n/TSEG (640).
__global__ __launch_bounds__(256) void kW(unsigned short* __restrict__ P,
                                          const float* __restrict__ md,
                                          float* __restrict__ attn) {
  int bj = blockIdx.x;
  int b = bj / NJ, j = bj - b * NJ;
  const float* mp = md + (size_t)b * (QSEG * 48);
  float ms[QSEG];
  float m = -1e30f;
#pragma unroll
  for (int s = 0; s < QSEG; ++s) { ms[s] = mp[s * 48 + j]; m = fmaxf(m, ms[s]); }
  float d = 0.f;
#pragma unroll
  for (int s = 0; s < QSEG; ++s) d += mp[s * 48 + 24 + j] * __expf(ms[s] - m);
  float rinv = 1.f / d;
  float cs[QSEG];
#pragma unroll
  for (int s = 0; s < QSEG; ++s) cs[s] = __expf(ms[s] - m) * rinv;

  unsigned* prow = (unsigned*)(P + (size_t)bj * KP);
  float2* arow = (float2*)(attn + (size_t)bj * NS);
  for (int i = threadIdx.x; i < NS / 2; i += 256) {
    unsigned pk = prow[i];
    int n0 = 2 * i;
    float p0 = bf2f(pk & 0xffffu) * cs[n0 / TSEG];
    float p1 = bf2f(pk >> 16) * cs[(n0 + 1) / TSEG];
    arow[i] = make_float2(p0, p1);
    prow[i] = (unsigned)f2bf(p0) | ((unsigned)f2bf(p1) << 16);
  }
  if (threadIdx.x < (KP - NS) / 2) prow[NS / 2 + threadIdx.x] = 0;   // k-pad zeros
}

// out[b][j][l] = attn_b @ X_b via MFMA (A rows clamped; rows>=24 feed discarded C rows)
__global__ __launch_bounds__(384) void k4(const unsigned short* __restrict__ Xt,
                                          const unsigned short* __restrict__ abf,
                                          float* __restrict__ out) {
  int bi = blockIdx.x;
  int b = bi / 3, ng = bi - 3 * b;
  int wid = threadIdx.x >> 6, lane = threadIdx.x & 63;
  int m = wid / 3, nt = wid - 3 * m;
  int col0 = ng * 48 + nt * 16;
  int lr = lane & 15, lg = lane >> 4;

  int arow = m * 16 + lr; if (arow > 23) arow = 23;
  const unsigned short* ap = abf + ((size_t)b * NJ + arow) * KP + lg * 8;
  const unsigned short* bp = Xt + (size_t)b * (144 * KP) + (size_t)(col0 + lr) * KP + lg * 8;

  f32x4 acc = {0.f, 0.f, 0.f, 0.f};
#pragma unroll 4
  for (int ks = 0; ks < KP / 32; ++ks) {
    short8 av = *(const short8*)(ap + ks * 32);
    short8 bv = *(const short8*)(bp + ks * 32);
    acc = mfma16(av, bv, acc);
  }
  int lcol = col0 + lr;
  if (lcol < DF) {
    int jb = m * 16 + lg * 4;
#pragma unroll
    for (int r = 0; r < 4; ++r) {
      int j = jb + r;
      if (j < NJ) out[(size_t)b * (NJ * DF) + (size_t)j * DF + lcol] = acc[r];
    }
  }
}

// =============== FP32 fallback (round-3, known-pass) ===============
#define KSEG 8
#define CSEG 313
#define SEGN 625
#define TN 64
#define LDP 132
#define WS_W1T 0u
#define WS_QTF 60000u
#define WS_MDF (WS_QTF + 804864u)
#define WS_PHF (WS_MDF + (unsigned)(NB * QSEG * 48))
#define SEGSTRIDE ((size_t)NB * NJ * DF)

__global__ __launch_bounds__(256) void kT_f(const float* __restrict__ W1,
                                            float* __restrict__ W1t) {
  int i = blockIdx.x * 256 + threadIdx.x;
  if (i >= NJ * NS) return;
  int o = i / NS, c = i - o * NS;
  W1t[c * NJ + o] = W1[i];
}

__global__ __launch_bounds__(192) void kH_f(const float* __restrict__ sf,
                                            const float* __restrict__ W1t,
                                            float* __restrict__ ph) {
  int b = blockIdx.x >> 3;
  int s = blockIdx.x & 7;
  int l = threadIdx.x;
  int c0 = s * CSEG;
  int cnt = NS - c0; if (cnt > CSEG) cnt = CSEG;
  const float* xp = sf + (size_t)b * (NS * DF) + (size_t)c0 * DF;
  const float* wp = W1t + (size_t)c0 * NJ;
  float acc[NJ];
#pragma unroll
  for (int o = 0; o < NJ; ++o) acc[o] = 0.f;
  if (l < DF) {
#pragma unroll 2
    for (int c = 0; c < cnt; ++c) {
      float xv = xp[(size_t)c * DF + l];
#pragma unroll
      for (int o = 0; o < NJ; ++o) acc[o] = fmaf(wp[c * NJ + o], xv, acc[o]);
    }
    float* pp = ph + (size_t)(s * NB + b) * (NJ * DF) + l;
#pragma unroll
    for (int o = 0; o < NJ; ++o) pp[o * DF] = acc[o];
  }
}

__global__ __launch_bounds__(512) void k1b_f(const float* __restrict__ ph,
                                             const float* __restrict__ W2,
                                             const float* __restrict__ b1v,
                                             const float* __restrict__ b2v,
                                             float* __restrict__ q_t) {
  int flat = blockIdx.x * 512 + threadIdx.x;
  if (flat >= NB * DF) return;
  int l = flat % DF;
  int b = flat / DF;
  const float* p0 = ph + (size_t)(b * NJ) * DF + l;
  float hv[NJ];
#pragma unroll
  for (int o = 0; o < NJ; ++o) hv[o] = b1v[o];
  for (int s = 0; s < KSEG; ++s) {
#pragma unroll
    for (int o = 0; o < NJ; ++o) hv[o] += p0[s * SEGSTRIDE + o * DF];
  }
#pragma unroll
  for (int o = 0; o < NJ; ++o) hv[o] = fmaxf(hv[o], 0.f);
  float q[NJ];
  for (int o = 0; o < NJ; ++o) {
    float sv = b2v[o];
#pragma unroll
    for (int i = 0; i < NJ; ++i) sv = fmaf(W2[o * NJ + i], hv[i], sv);
    q[o] = sv;
  }
  float4* qp = (float4*)(q_t + (size_t)flat * NJ);
#pragma unroll
  for (int v = 0; v < 6; ++v)
    qp[v] = make_float4(q[4 * v], q[4 * v + 1], q[4 * v + 2], q[4 * v + 3]);
}

__global__ __launch_bounds__(256) void k2_f(const float* __restrict__ sf,
                                            const float* __restrict__ q_t,
                                            float* __restrict__ raw,
                                            float* __restrict__ md) {
  __shared__ __align__(16) float xs[TN * LDP];
  int b = blockIdx.x >> 2;
  int s = blockIdx.x & 3;
  int tid = threadIdx.x;
  int wid = tid >> 6, lane = tid & 63;
  int jq = __builtin_amdgcn_readfirstlane(wid);

  const float* sft = sf + (size_t)b * (NS * DF) + (size_t)(s * SEGN) * DF;
  const float* qb = q_t + (size_t)b * (DF * NJ) + jq * 6;
  float* rawb = raw + (size_t)b * (NJ * NS) + (size_t)(s * SEGN);

  float m6[6], d6[6];
#pragma unroll
  for (int i = 0; i < 6; ++i) { m6[i] = -1e30f; d6[i] = 0.f; }

  const int NT = (SEGN + TN - 1) / TN;
  for (int t = 0; t < NT; ++t) {
    int n0 = t * TN;
    int nmax = SEGN - n0; if (nmax > TN) nmax = TN;
    __syncthreads();
#pragma unroll
    for (int rr = 0; rr < 16; ++rr) {
      int r = wid * 16 + rr;
      if (r < nmax) {
        const float* g = sft + (size_t)(n0 + r) * DF;
        float* d = xs + r * LDP;
        d[lane] = g[lane];
        d[64 + lane] = g[64 + lane];
        if (lane < 3) d[128 + lane] = g[128 + lane];
      }
    }
    __syncthreads();
    if (lane < nmax) {
      const float* xrow = xs + lane * LDP;
      float sa[6];
#pragma unroll
      for (int i = 0; i < 6; ++i) sa[i] = 0.f;
      for (int l4 = 0; l4 < 32; ++l4) {
        float4 xv = *(const float4*)(xrow + 4 * l4);
        const float* q4 = qb + (4 * l4) * NJ;
#pragma unroll
        for (int i = 0; i < 6; ++i) sa[i] = fmaf(q4[i], xv.x, sa[i]);
#pragma unroll
        for (int i = 0; i < 6; ++i) sa[i] = fmaf(q4[NJ + i], xv.y, sa[i]);
#pragma unroll
        for (int i = 0; i < 6; ++i) sa[i] = fmaf(q4[2 * NJ + i], xv.z, sa[i]);
#pragma unroll
        for (int i = 0; i < 6; ++i) sa[i] = fmaf(q4[3 * NJ + i], xv.w, sa[i]);
      }
#pragma unroll
      for (int l = 128; l < DF; ++l) {
        float xv = xrow[l];
#pragma unroll
        for (int i = 0; i < 6; ++i) sa[i] = fmaf(qb[l * NJ + i], xv, sa[i]);
      }
      int nr = n0 + lane;
#pragma unroll
      for (int i = 0; i < 6; ++i) {
        rawb[(size_t)(jq * 6 + i) * NS + nr] = sa[i];
        float mn = fmaxf(m6[i], sa[i]);
        d6[i] = d6[i] * __expf(m6[i] - mn) + __expf(sa[i] - mn);
        m6[i] = mn;
      }
    }
  }
#pragma unroll
  for (int i = 0; i < 6; ++i) {
    float m = m6[i], d = d6[i];
    for (int off = 32; off > 0; off >>= 1) {
      float mo = __shfl_xor(m, off);
      float dd = __shfl_xor(d, off);
      float nm = fmaxf(m, mo);
      d = d * __expf(m - nm) + dd * __expf(mo - nm);
      m = nm;
    }
    m6[i] = m; d6[i] = d;
  }
  if (lane == 0) {
    float* mp = md + ((size_t)b * QSEG + s) * 48;
#pragma unroll
    for (int i = 0; i < 6; ++i) {
      mp[jq * 6 + i] = m6[i];
      mp[24 + jq * 6 + i] = d6[i];
    }
  }
}

__global__ __launch_bounds__(256) void k3_f(float* __restrict__ attn,
                                            const float* __restrict__ md) {
  int bj = blockIdx.x;
  int b = bj / NJ;
  int j = bj - b * NJ;
  const float* mp = md + (size_t)b * (QSEG * 48);
  float m = -1e30f, d = 0.f;
#pragma unroll
  for (int s = 0; s < QSEG; ++s) {
    float ms = mp[s * 48 + j], ds = mp[s * 48 + 24 + j];
    float nm = fmaxf(m, ms);
    d = d * __expf(m - nm) + ds * __expf(ms - nm);
    m = nm;
  }
  float r = 1.f / d;
  float* p = attn + (size_t)bj * NS;
  for (int n = threadIdx.x; n < NS; n += 256)
    p[n] = __expf(p[n] - m) * r;
}

__global__ __launch_bounds__(192) void k4_f(const float* __restrict__ sf,
                                            const float* __restrict__ attn,
                                            float* __restrict__ po) {
  int b = blockIdx.x >> 3;
  int s = blockIdx.x & 7;
  int l = threadIdx.x;
  int n0 = s * CSEG;
  int cnt = NS - n0; if (cnt > CSEG) cnt = CSEG;
  const float* xp = sf + (size_t)b * (NS * DF) + (size_t)n0 * DF;
  const float* ap = attn + (size_t)b * (NJ * NS) + n0;
  float acc[NJ];
#pragma unroll
  for (int o = 0; o < NJ; ++o) acc[o] = 0.f;
  if (l < DF) {
#pragma unroll 2
    for (int n = 0; n < cnt; ++n) {
      float xv = xp[(size_t)n * DF + l];
#pragma unroll
      for (int o = 0; o < NJ; ++o) acc[o] = fmaf(ap[(size_t)o * NS + n], xv, acc[o]);
    }
    float* pp = po + (size_t)(s * NB + b) * (NJ * DF) + l;
#pragma unroll
    for (int o = 0; o < NJ; ++o) pp[o * DF] = acc[o];
  }
}

__global__ __launch_bounds__(512) void k5_f(const float* __restrict__ po,
                                            float* __restrict__ out) {
  int i = blockIdx.x * 512 + threadIdx.x;
  float v = 0.f;
#pragma unroll
  for (int s = 0; s < KSEG; ++s) v += po[s * SEGSTRIDE + i];
  out[i] = v;
}

extern "C" void kernel_launch(void* const* d_in, const int* in_sizes, int n_in,
                              void* d_out, int out_size, void* d_ws, size_t ws_size,
                              hipStream_t stream) {
  const float* sf = (const float*)d_in[0];
  const float* W1 = (const float*)d_in[1];
  const float* b1 = (const float*)d_in[2];
  const float* W2 = (const float*)d_in[3];
  const float* b2 = (const float*)d_in[4];
  float* out = (float*)d_out;
  float* attn = out + (size_t)NB * NJ * DF;

  if (ws_size >= WS_FULL) {
    unsigned short* Xt  = (unsigned short*)((char*)d_ws + F_XT);
    unsigned short* Xn  = (unsigned short*)((char*)d_ws + F_XN);
    unsigned short* W1b = (unsigned short*)((char*)d_ws + F_W1B);
    unsigned short* qbf = (unsigned short*)((char*)d_ws + F_QBF);
    float* hbuf = (float*)((char*)d_ws + F_H);
    float* md   = (float*)((char*)d_ws + F_MD);
    unsigned short* P   = (unsigned short*)((char*)d_ws + F_P);

    kT2<<<158, 256, 0, stream>>>(W1, W1b);
    kP2<<<NB * 20, 256, 0, stream>>>(sf, Xt, Xn);
    kH <<<NB * 3, 384, 0, stream>>>(Xt, W1b, hbuf);
    k1b<<<80, 512, 0, stream>>>(hbuf, W2, b1, b2, qbf);
    k2m<<<NB * QSEG, 512, 0, stream>>>(Xn, qbf, P, md);
    kW <<<NB * NJ, 256, 0, stream>>>(P, md, attn);
    k4 <<<NB * 3, 384, 0, stream>>>(Xt, P, out);
  } else {
    float* ws = (float*)d_ws;
    float* W1t = ws + WS_W1T;
    float* q_t = ws + WS_QTF;
    float* md  = ws + WS_MDF;
    float* ph  = ws + WS_PHF;
    kT_f <<<235, 256, 0, stream>>>(W1, W1t);
    kH_f <<<NB * KSEG, 192, 0, stream>>>(sf, W1t, ph);
    k1b_f<<<66, 512, 0, stream>>>(ph, W2, b1, b2, q_t);
    k2_f <<<NB * QSEG, 256, 0, stream>>>(sf, q_t, attn, md);
    k3_f <<<NB * NJ, 256, 0, stream>>>(attn, md);
    k4_f <<<NB * KSEG, 192, 0, stream>>>(sf, attn, ph);
    k5_f <<<1572, 512, 0, stream>>>(ph, out);
  }
}

// Round 10
// 463.009 us; speedup vs baseline: 1.1202x; 1.1202x over previous
//
#include <hip/hip_runtime.h>
#include <cstdint>
#include <cstddef>

#define NB 256
#define NS 2500
#define NJ 24
#define DF 131

#define QSEG 4           // n segments for k2m (md interface)
#define TSEG 640         // k2m/kW TILE-partition segment size: 40 tiles of 16

#define KP 2528          // padded K (c) for MFMA, 79 steps of 32
#define XNROWS 2512      // 157 tiles of 16
#define LP 160           // padded l for score MFMA (5 k-steps of 32)

using short8 = __attribute__((ext_vector_type(8))) short;
using f32x4  = __attribute__((ext_vector_type(4))) float;

// ---- FULL-path ws byte offsets ----
#define F_XT   0ull                        // [NB][144][KP] bf16
#define F_XN   186384384ull                // [NB][XNROWS][LP] bf16
#define F_W1B  392167424ull                // [32][KP] bf16
#define F_QBF  392329216ull                // [NB][32][LP] bf16
#define F_H    394950656ull                // [NB][NJ][DF] f32
#define F_MD   398170112ull                // [NB][QSEG][48] f32
#define F_P    398366720ull                // [NB][NJ][KP] bf16
#define WS_FULL 429430784ull

__device__ __forceinline__ unsigned short f2bf(float x) {
  union { float f; unsigned u; } v; v.f = x;
  unsigned r = v.u + 0x7fffu + ((v.u >> 16) & 1u);   // RNE
  return (unsigned short)(r >> 16);
}
__device__ __forceinline__ float bf2f(unsigned us) {
  union { unsigned u; float f; } v; v.u = us << 16;
  return v.f;
}
__device__ __forceinline__ f32x4 mfma16(short8 a, short8 b, f32x4 c) {
  return __builtin_amdgcn_mfma_f32_16x16x32_bf16(a, b, c, 0, 0, 0);
}

// W1 [24][2500] f32 -> W1b [32][KP] bf16, zero-padded
__global__ __launch_bounds__(256) void kT2(const float* __restrict__ W1,
                                           unsigned short* __restrict__ W1b) {
  int dwi = blockIdx.x * 256 + threadIdx.x;
  if (dwi >= 32 * (KP / 2)) return;
  int row = dwi / (KP / 2);
  int kk = (dwi - row * (KP / 2)) * 2;
  unsigned lo = (row < NJ && kk     < NS) ? f2bf(W1[row * NS + kk])     : 0;
  unsigned hi = (row < NJ && kk + 1 < NS) ? f2bf(W1[row * NS + kk + 1]) : 0;
  ((unsigned*)W1b)[dwi] = lo | (hi << 16);
}

// X f32 [b][c][l] -> Xt bf16 [b][l][c-pad] + Xn bf16 [b][c][l-pad].
// LDS pad 133 shorts (round-5 proven: phase-2a lane stride 133 dwords, odd -> 2-way free).
// Phase 2b: u16-pair LDS readback (stride-1 dwords, free) + coalesced dword stores.
__global__ __launch_bounds__(256) void kP2(const float* __restrict__ sf,
                                           unsigned short* __restrict__ Xt,
                                           unsigned short* __restrict__ Xn) {
  __shared__ unsigned short xs[128 * 133];         // 34048 B
  int b = blockIdx.x / 20;
  int chunk = blockIdx.x - 20 * b;
  int c0 = chunk * 128;
  int w = threadIdx.x >> 6, lane = threadIdx.x & 63;
  const float* xb = sf + (size_t)b * (NS * DF);

  // phase 1: coalesced f32 row reads, convert, u16 LDS stores (rows >= NS zeroed)
  for (int i = 0; i < 32; ++i) {
    int r = w * 32 + i;
    int c = c0 + r;
    bool vc = c < NS;
    const float* g = xb + (size_t)c * DF;
    float v0 = vc ? g[lane] : 0.f;
    float v1 = vc ? g[64 + lane] : 0.f;
    float v2 = (vc && lane < 3) ? g[128 + lane] : 0.f;
    xs[r * 133 + lane] = f2bf(v0);
    xs[r * 133 + 64 + lane] = f2bf(v1);
    if (lane < 3) xs[r * 133 + 128 + lane] = f2bf(v2);
  }
  __syncthreads();

  // phase 2a: Xt[l][cc,cc+1] dword stores (round-5 proven, 2-way LDS = free)
  int cc = c0 + 2 * lane;
  if (cc < KP) {
    unsigned short* xtb = Xt + (size_t)b * (144 * KP);
    for (int l = w; l < DF; l += 4) {
      unsigned lo = xs[(2 * lane) * 133 + l];      // lane stride 133 dwords (odd)
      unsigned hi = xs[(2 * lane + 1) * 133 + l];
      *(unsigned*)(xtb + (size_t)l * KP + cc) = lo | (hi << 16);
    }
  }
  // phase 2b: Xn rows via u16-pair readback (stride-1 dword banks) + dword stores
  if (Xn) {
    unsigned* xnb = (unsigned*)(Xn + (size_t)b * (XNROWS * LP));
    for (int i = 0; i < 32; ++i) {
      int r = w * 32 + i;
      int c = c0 + r;
      if (c < XNROWS) {
        unsigned lo = xs[r * 133 + 2 * lane];      // 64 consecutive dwords: free
        unsigned hi = xs[r * 133 + 2 * lane + 1];
        xnb[(size_t)c * (LP / 2) + lane] = lo | (hi << 16);   // 256B coalesced
        if (lane < 16) {                           // dwords 64..79 = l 128..159
          unsigned v = 0;
          if (lane == 0)
            v = (unsigned)xs[r * 133 + 128] | ((unsigned)xs[r * 133 + 129] << 16);
          else if (lane == 1)
            v = (unsigned)xs[r * 133 + 130];       // l=131 pad zero
          xnb[(size_t)c * (LP / 2) + 64 + lane] = v;
        }
      }
    }
  }
}

// h[b][j][l] = (W1 @ X_b) via MFMA
__global__ __launch_bounds__(384) void kH(const unsigned short* __restrict__ Xt,
                                          const unsigned short* __restrict__ W1b,
                                          float* __restrict__ h) {
  int bi = blockIdx.x;
  int b = bi / 3, ng = bi - 3 * b;
  int wid = threadIdx.x >> 6, lane = threadIdx.x & 63;
  int m = wid / 3, nt = wid - 3 * m;
  int col0 = ng * 48 + nt * 16;
  int lr = lane & 15, lg = lane >> 4;

  const unsigned short* ap = W1b + (size_t)(m * 16 + lr) * KP + lg * 8;
  const unsigned short* bp = Xt + (size_t)b * (144 * KP) + (size_t)(col0 + lr) * KP + lg * 8;

  f32x4 acc = {0.f, 0.f, 0.f, 0.f};
#pragma unroll 4
  for (int ks = 0; ks < KP / 32; ++ks) {
    short8 av = *(const short8*)(ap + ks * 32);
    short8 bv = *(const short8*)(bp + ks * 32);
    acc = mfma16(av, bv, acc);
  }
  int lcol = col0 + lr;
  if (lcol < DF) {
    int jb = m * 16 + lg * 4;
#pragma unroll
    for (int r = 0; r < 4; ++r) {
      int j = jb + r;
      if (j < NJ) h[(size_t)b * (NJ * DF) + (size_t)j * DF + lcol] = acc[r];
    }
  }
}

// relu(h+b1) -> q = W2@. + b2 -> qbf bf16 [b][32][LP]
__global__ __launch_bounds__(512) void k1b(const float* __restrict__ h,
                                           const float* __restrict__ W2,
                                           const float* __restrict__ b1v,
                                           const float* __restrict__ b2v,
                                           unsigned short* __restrict__ qbf) {
  int flat = blockIdx.x * 512 + threadIdx.x;      // NB*LP threads
  if (flat >= NB * LP) return;
  int l = flat % LP;
  int b = flat / LP;
  unsigned short* qp = qbf + (size_t)b * (32 * LP) + l;
  if (l >= DF) {
#pragma unroll
    for (int j = 0; j < 32; ++j) qp[j * LP] = 0;
    return;
  }
  const float* p0 = h + (size_t)b * (NJ * DF) + l;
  float hv[NJ];
#pragma unroll
  for (int o = 0; o < NJ; ++o) hv[o] = fmaxf(b1v[o] + p0[o * DF], 0.f);
  float q[NJ];
  for (int o = 0; o < NJ; ++o) {
    float sv = b2v[o];
#pragma unroll
    for (int i = 0; i < NJ; ++i) sv = fmaf(W2[o * NJ + i], hv[i], sv);
    q[o] = sv;
  }
#pragma unroll
  for (int j = 0; j < NJ; ++j) qp[j * LP] = f2bf(q[j]);
#pragma unroll
  for (int j = NJ; j < 32; ++j) qp[j * LP] = 0;
}

// MFMA scores from Xn (bf16, 16B-aligned short8 loads), two-pass-in-registers:
// P = exp(S - m_seg) bf16 + per-seg (m,d). n partition BY TILES: seg = n/640.
__global__ __launch_bounds__(512) void k2m(const unsigned short* __restrict__ Xn,
                                           const unsigned short* __restrict__ qbf,
                                           unsigned short* __restrict__ P,
                                           float* __restrict__ md) {
  __shared__ float wm[8][24];
  __shared__ float wd[8][24];
  int b = blockIdx.x >> 2, seg = blockIdx.x & 3;
  int w = threadIdx.x >> 6, lane = threadIdx.x & 63;
  int lr = lane & 15, lg = lane >> 4;

  const unsigned short* qb = qbf + (size_t)b * (32 * LP);
  short8 aq0[5], aq1[5];
#pragma unroll
  for (int ks = 0; ks < 5; ++ks) {
    aq0[ks] = *(const short8*)(qb + (size_t)lr * LP + ks * 32 + lg * 8);
    aq1[ks] = *(const short8*)(qb + (size_t)(16 + lr) * LP + ks * 32 + lg * 8);
  }
  const unsigned short* xb = Xn + (size_t)b * (XNROWS * LP);
  int ntl = (seg < 3) ? 40 : 37;

  f32x4 s0[5], s1[5];
  float m8[8];
#pragma unroll
  for (int r = 0; r < 8; ++r) m8[r] = -1e30f;

#pragma unroll
  for (int i = 0; i < 5; ++i) {
    s0[i] = (f32x4){0.f, 0.f, 0.f, 0.f};
    s1[i] = (f32x4){0.f, 0.f, 0.f, 0.f};
    int ti = w + 8 * i;
    if (ti < ntl) {
      int n = (seg * 40 + ti) * 16 + lr;
      const unsigned short* bp = xb + (size_t)n * LP + lg * 8;
      short8 bx[5];
#pragma unroll
      for (int ks = 0; ks < 5; ++ks) bx[ks] = *(const short8*)(bp + ks * 32);
      f32x4 a0 = {0.f, 0.f, 0.f, 0.f}, a1 = {0.f, 0.f, 0.f, 0.f};
#pragma unroll
      for (int ks = 0; ks < 5; ++ks) {
        a0 = mfma16(aq0[ks], bx[ks], a0);
        a1 = mfma16(aq1[ks], bx[ks], a1);
      }
      s0[i] = a0; s1[i] = a1;
#pragma unroll
      for (int r = 0; r < 4; ++r) {
        m8[r]     = fmaxf(m8[r],     a0[r]);
        m8[4 + r] = fmaxf(m8[4 + r], a1[r]);
      }
    }
  }
  // max over 16 n-lanes
#pragma unroll
  for (int r = 0; r < 8; ++r)
#pragma unroll
    for (int off = 1; off < 16; off <<= 1)
      m8[r] = fmaxf(m8[r], __shfl_xor(m8[r], off));
  if (lr == 0) {
#pragma unroll
    for (int r = 0; r < 4; ++r) {
      wm[w][lg * 4 + r] = m8[r];
      if (lg < 2) wm[w][16 + lg * 4 + r] = m8[4 + r];
    }
  }
  __syncthreads();
  float mseg[8];
#pragma unroll
  for (int r = 0; r < 4; ++r) {
    float m0 = wm[0][lg * 4 + r];
#pragma unroll
    for (int wv = 1; wv < 8; ++wv) m0 = fmaxf(m0, wm[wv][lg * 4 + r]);
    mseg[r] = m0;
    int j1 = 16 + (lg & 1) * 4 + r;
    float m1 = wm[0][j1];
#pragma unroll
    for (int wv = 1; wv < 8; ++wv) m1 = fmaxf(m1, wm[wv][j1]);
    mseg[4 + r] = m1;
  }
  float d8[8];
#pragma unroll
  for (int r = 0; r < 8; ++r) d8[r] = 0.f;
#pragma unroll
  for (int i = 0; i < 5; ++i) {
    int ti = w + 8 * i;
    if (ti < ntl) {
      int n = (seg * 40 + ti) * 16 + lr;
      bool valid = n < NS;
#pragma unroll
      for (int r = 0; r < 4; ++r) {
        float p0 = __expf(s0[i][r] - mseg[r]);
        float p1 = __expf(s1[i][r] - mseg[4 + r]);
        if (valid) {
          P[((size_t)b * NJ + lg * 4 + r) * KP + n] = f2bf(p0);
          d8[r] += p0;
          if (lg < 2) {
            P[((size_t)b * NJ + 16 + lg * 4 + r) * KP + n] = f2bf(p1);
            d8[4 + r] += p1;
          }
        }
      }
    }
  }
#pragma unroll
  for (int r = 0; r < 8; ++r)
#pragma unroll
    for (int off = 1; off < 16; off <<= 1)
      d8[r] += __shfl_xor(d8[r], off);
  if (lr == 0) {
#pragma unroll
    for (int r = 0; r < 4; ++r) {
      wd[w][lg * 4 + r] = d8[r];
      if (lg < 2) wd[w][16 + lg * 4 + r] = d8[4 + r];
    }
  }
  __syncthreads();
  if (threadIdx.x < NJ) {
    int j = threadIdx.x;
    float m = wm[0][j], d = 0.f;
#pragma unroll
    for (int wv = 1; wv < 8; ++wv) m = fmaxf(m, wm[wv][j]);
#pragma unroll
    for (int wv = 0; wv < 8; ++wv) d += wd[wv][j];
    float* mp = md + ((size_t)b * QSEG + seg) * 48;
    mp[j] = m;
    mp[24 + j] = d;
  }
}

// combine md; write attention f32 (required output) + normalize P bf16 in place.
// Segment of n is the TILE partition n/TSEG (640).
__global__ __launch_bounds__(256) void kW(unsigned short* __restrict__ P,
                                          const float* __restrict__ md,
                                          float* __restrict__ attn) {
  int bj = blockIdx.x;
  int b = bj / NJ, j = bj - b * NJ;
  const float* mp = md + (size_t)b * (QSEG * 48);
  float ms[QSEG];
  float m = -1e30f;
#pragma unroll
  for (int s = 0; s < QSEG; ++s) { ms[s] = mp[s * 48 + j]; m = fmaxf(m, ms[s]); }
  float d = 0.f;
#pragma unroll
  for (int s = 0; s < QSEG; ++s) d += mp[s * 48 + 24 + j] * __expf(ms[s] - m);
  float rinv = 1.f / d;
  float cs[QSEG];
#pragma unroll
  for (int s = 0; s < QSEG; ++s) cs[s] = __expf(ms[s] - m) * rinv;

  unsigned* prow = (unsigned*)(P + (size_t)bj * KP);
  float2* arow = (float2*)(attn + (size_t)bj * NS);
  for (int i = threadIdx.x; i < NS / 2; i += 256) {
    unsigned pk = prow[i];
    int n0 = 2 * i;
    float p0 = bf2f(pk & 0xffffu) * cs[n0 / TSEG];
    float p1 = bf2f(pk >> 16) * cs[(n0 + 1) / TSEG];
    arow[i] = make_float2(p0, p1);
    prow[i] = (unsigned)f2bf(p0) | ((unsigned)f2bf(p1) << 16);
  }
  if (threadIdx.x < (KP - NS) / 2) prow[NS / 2 + threadIdx.x] = 0;   // k-pad zeros
}

// out[b][j][l] = attn_b @ X_b via MFMA (A rows clamped; rows>=24 feed discarded C rows)
__global__ __launch_bounds__(384) void k4(const unsigned short* __restrict__ Xt,
                                          const unsigned short* __restrict__ abf,
                                          float* __restrict__ out) {
  int bi = blockIdx.x;
  int b = bi / 3, ng = bi - 3 * b;
  int wid = threadIdx.x >> 6, lane = threadIdx.x & 63;
  int m = wid / 3, nt = wid - 3 * m;
  int col0 = ng * 48 + nt * 16;
  int lr = lane & 15, lg = lane >> 4;

  int arow = m * 16 + lr; if (arow > 23) arow = 23;
  const unsigned short* ap = abf + ((size_t)b * NJ + arow) * KP + lg * 8;
  const unsigned short* bp = Xt + (size_t)b * (144 * KP) + (size_t)(col0 + lr) * KP + lg * 8;

  f32x4 acc = {0.f, 0.f, 0.f, 0.f};
#pragma unroll 4
  for (int ks = 0; ks < KP / 32; ++ks) {
    short8 av = *(const short8*)(ap + ks * 32);
    short8 bv = *(const short8*)(bp + ks * 32);
    acc = mfma16(av, bv, acc);
  }
  int lcol = col0 + lr;
  if (lcol < DF) {
    int jb = m * 16 + lg * 4;
#pragma unroll
    for (int r = 0; r < 4; ++r) {
      int j = jb + r;
      if (j < NJ) out[(size_t)b * (NJ * DF) + (size_t)j * DF + lcol] = acc[r];
    }
  }
}

// =============== FP32 fallback (round-3, known-pass) ===============
#define KSEG 8
#define CSEG 313
#define SEGN 625
#define TN 64
#define LDP 132
#define WS_W1T 0u
#define WS_QTF 60000u
#define WS_MDF (WS_QTF + 804864u)
#define WS_PHF (WS_MDF + (unsigned)(NB * QSEG * 48))
#define SEGSTRIDE ((size_t)NB * NJ * DF)

__global__ __launch_bounds__(256) void kT_f(const float* __restrict__ W1,
                                            float* __restrict__ W1t) {
  int i = blockIdx.x * 256 + threadIdx.x;
  if (i >= NJ * NS) return;
  int o = i / NS, c = i - o * NS;
  W1t[c * NJ + o] = W1[i];
}

__global__ __launch_bounds__(192) void kH_f(const float* __restrict__ sf,
                                            const float* __restrict__ W1t,
                                            float* __restrict__ ph) {
  int b = blockIdx.x >> 3;
  int s = blockIdx.x & 7;
  int l = threadIdx.x;
  int c0 = s * CSEG;
  int cnt = NS - c0; if (cnt > CSEG) cnt = CSEG;
  const float* xp = sf + (size_t)b * (NS * DF) + (size_t)c0 * DF;
  const float* wp = W1t + (size_t)c0 * NJ;
  float acc[NJ];
#pragma unroll
  for (int o = 0; o < NJ; ++o) acc[o] = 0.f;
  if (l < DF) {
#pragma unroll 2
    for (int c = 0; c < cnt; ++c) {
      float xv = xp[(size_t)c * DF + l];
#pragma unroll
      for (int o = 0; o < NJ; ++o) acc[o] = fmaf(wp[c * NJ + o], xv, acc[o]);
    }
    float* pp = ph + (size_t)(s * NB + b) * (NJ * DF) + l;
#pragma unroll
    for (int o = 0; o < NJ; ++o) pp[o * DF] = acc[o];
  }
}

__global__ __launch_bounds__(512) void k1b_f(const float* __restrict__ ph,
                                             const float* __restrict__ W2,
                                             const float* __restrict__ b1v,
                                             const float* __restrict__ b2v,
                                             float* __restrict__ q_t) {
  int flat = blockIdx.x * 512 + threadIdx.x;
  if (flat >= NB * DF) return;
  int l = flat % DF;
  int b = flat / DF;
  const float* p0 = ph + (size_t)(b * NJ) * DF + l;
  float hv[NJ];
#pragma unroll
  for (int o = 0; o < NJ; ++o) hv[o] = b1v[o];
  for (int s = 0; s < KSEG; ++s) {
#pragma unroll
    for (int o = 0; o < NJ; ++o) hv[o] += p0[s * SEGSTRIDE + o * DF];
  }
#pragma unroll
  for (int o = 0; o < NJ; ++o) hv[o] = fmaxf(hv[o], 0.f);
  float q[NJ];
  for (int o = 0; o < NJ; ++o) {
    float sv = b2v[o];
#pragma unroll
    for (int i = 0; i < NJ; ++i) sv = fmaf(W2[o * NJ + i], hv[i], sv);
    q[o] = sv;
  }
  float4* qp = (float4*)(q_t + (size_t)flat * NJ);
#pragma unroll
  for (int v = 0; v < 6; ++v)
    qp[v] = make_float4(q[4 * v], q[4 * v + 1], q[4 * v + 2], q[4 * v + 3]);
}

__global__ __launch_bounds__(256) void k2_f(const float* __restrict__ sf,
                                            const float* __restrict__ q_t,
                                            float* __restrict__ raw,
                                            float* __restrict__ md) {
  __shared__ __align__(16) float xs[TN * LDP];
  int b = blockIdx.x >> 2;
  int s = blockIdx.x & 3;
  int tid = threadIdx.x;
  int wid = tid >> 6, lane = tid & 63;
  int jq = __builtin_amdgcn_readfirstlane(wid);

  const float* sft = sf + (size_t)b * (NS * DF) + (size_t)(s * SEGN) * DF;
  const float* qb = q_t + (size_t)b * (DF * NJ) + jq * 6;
  float* rawb = raw + (size_t)b * (NJ * NS) + (size_t)(s * SEGN);

  float m6[6], d6[6];
#pragma unroll
  for (int i = 0; i < 6; ++i) { m6[i] = -1e30f; d6[i] = 0.f; }

  const int NT = (SEGN + TN - 1) / TN;
  for (int t = 0; t < NT; ++t) {
    int n0 = t * TN;
    int nmax = SEGN - n0; if (nmax > TN) nmax = TN;
    __syncthreads();
#pragma unroll
    for (int rr = 0; rr < 16; ++rr) {
      int r = wid * 16 + rr;
      if (r < nmax) {
        const float* g = sft + (size_t)(n0 + r) * DF;
        float* d = xs + r * LDP;
        d[lane] = g[lane];
        d[64 + lane] = g[64 + lane];
        if (lane < 3) d[128 + lane] = g[128 + lane];
      }
    }
    __syncthreads();
    if (lane < nmax) {
      const float* xrow = xs + lane * LDP;
      float sa[6];
#pragma unroll
      for (int i = 0; i < 6; ++i) sa[i] = 0.f;
      for (int l4 = 0; l4 < 32; ++l4) {
        float4 xv = *(const float4*)(xrow + 4 * l4);
        const float* q4 = qb + (4 * l4) * NJ;
#pragma unroll
        for (int i = 0; i < 6; ++i) sa[i] = fmaf(q4[i], xv.x, sa[i]);
#pragma unroll
        for (int i = 0; i < 6; ++i) sa[i] = fmaf(q4[NJ + i], xv.y, sa[i]);
#pragma unroll
        for (int i = 0; i < 6; ++i) sa[i] = fmaf(q4[2 * NJ + i], xv.z, sa[i]);
#pragma unroll
        for (int i = 0; i < 6; ++i) sa[i] = fmaf(q4[3 * NJ + i], xv.w, sa[i]);
      }
#pragma unroll
      for (int l = 128; l < DF; ++l) {
        float xv = xrow[l];
#pragma unroll
        for (int i = 0; i < 6; ++i) sa[i] = fmaf(qb[l * NJ + i], xv, sa[i]);
      }
      int nr = n0 + lane;
#pragma unroll
      for (int i = 0; i < 6; ++i) {
        rawb[(size_t)(jq * 6 + i) * NS + nr] = sa[i];
        float mn = fmaxf(m6[i], sa[i]);
        d6[i] = d6[i] * __expf(m6[i] - mn) + __expf(sa[i] - mn);
        m6[i] = mn;
      }
    }
  }
#pragma unroll
  for (int i = 0; i < 6; ++i) {
    float m = m6[i], d = d6[i];
    for (int off = 32; off > 0; off >>= 1) {
      float mo = __shfl_xor(m, off);
      float dd = __shfl_xor(d, off);
      float nm = fmaxf(m, mo);
      d = d * __expf(m - nm) + dd * __expf(mo - nm);
      m = nm;
    }
    m6[i] = m; d6[i] = d;
  }
  if (lane == 0) {
    float* mp = md + ((size_t)b * QSEG + s) * 48;
#pragma unroll
    for (int i = 0; i < 6; ++i) {
      mp[jq * 6 + i] = m6[i];
      mp[24 + jq * 6 + i] = d6[i];
    }
  }
}

__global__ __launch_bounds__(256) void k3_f(float* __restrict__ attn,
                                            const float* __restrict__ md) {
  int bj = blockIdx.x;
  int b = bj / NJ;
  int j = bj - b * NJ;
  const float* mp = md + (size_t)b * (QSEG * 48);
  float m = -1e30f, d = 0.f;
#pragma unroll
  for (int s = 0; s < QSEG; ++s) {
    float ms = mp[s * 48 + j], ds = mp[s * 48 + 24 + j];
    float nm = fmaxf(m, ms);
    d = d * __expf(m - nm) + ds * __expf(ms - nm);
    m = nm;
  }
  float r = 1.f / d;
  float* p = attn + (size_t)bj * NS;
  for (int n = threadIdx.x; n < NS; n += 256)
    p[n] = __expf(p[n] - m) * r;
}

__global__ __launch_bounds__(192) void k4_f(const float* __restrict__ sf,
                                            const float* __restrict__ attn,
                                            float* __restrict__ po) {
  int b = blockIdx.x >> 3;
  int s = blockIdx.x & 7;
  int l = threadIdx.x;
  int n0 = s * CSEG;
  int cnt = NS - n0; if (cnt > CSEG) cnt = CSEG;
  const float* xp = sf + (size_t)b * (NS * DF) + (size_t)n0 * DF;
  const float* ap = attn + (size_t)b * (NJ * NS) + n0;
  float acc[NJ];
#pragma unroll
  for (int o = 0; o < NJ; ++o) acc[o] = 0.f;
  if (l < DF) {
#pragma unroll 2
    for (int n = 0; n < cnt; ++n) {
      float xv = xp[(size_t)n * DF + l];
#pragma unroll
      for (int o = 0; o < NJ; ++o) acc[o] = fmaf(ap[(size_t)o * NS + n], xv, acc[o]);
    }
    float* pp = po + (size_t)(s * NB + b) * (NJ * DF) + l;
#pragma unroll
    for (int o = 0; o < NJ; ++o) pp[o * DF] = acc[o];
  }
}

__global__ __launch_bounds__(512) void k5_f(const float* __restrict__ po,
                                            float* __restrict__ out) {
  int i = blockIdx.x * 512 + threadIdx.x;
  float v = 0.f;
#pragma unroll
  for (int s = 0; s < KSEG; ++s) v += po[s * SEGSTRIDE + i];
  out[i] = v;
}

extern "C" void kernel_launch(void* const* d_in, const int* in_sizes, int n_in,
                              void* d_out, int out_size, void* d_ws, size_t ws_size,
                              hipStream_t stream) {
  const float* sf = (const float*)d_in[0];
  const float* W1 = (const float*)d_in[1];
  const float* b1 = (const float*)d_in[2];
  const float* W2 = (const float*)d_in[3];
  const float* b2 = (const float*)d_in[4];
  float* out = (float*)d_out;
  float* attn = out + (size_t)NB * NJ * DF;

  if (ws_size >= WS_FULL) {
    unsigned short* Xt  = (unsigned short*)((char*)d_ws + F_XT);
    unsigned short* Xn  = (unsigned short*)((char*)d_ws + F_XN);
    unsigned short* W1b = (unsigned short*)((char*)d_ws + F_W1B);
    unsigned short* qbf = (unsigned short*)((char*)d_ws + F_QBF);
    float* hbuf = (float*)((char*)d_ws + F_H);
    float* md   = (float*)((char*)d_ws + F_MD);
    unsigned short* P   = (unsigned short*)((char*)d_ws + F_P);

    kT2<<<158, 256, 0, stream>>>(W1, W1b);
    kP2<<<NB * 20, 256, 0, stream>>>(sf, Xt, Xn);
    kH <<<NB * 3, 384, 0, stream>>>(Xt, W1b, hbuf);
    k1b<<<80, 512, 0, stream>>>(hbuf, W2, b1, b2, qbf);
    k2m<<<NB * QSEG, 512, 0, stream>>>(Xn, qbf, P, md);
    kW <<<NB * NJ, 256, 0, stream>>>(P, md, attn);
    k4 <<<NB * 3, 384, 0, stream>>>(Xt, P, out);
  } else {
    float* ws = (float*)d_ws;
    float* W1t = ws + WS_W1T;
    float* q_t = ws + WS_QTF;
    float* md  = ws + WS_MDF;
    float* ph  = ws + WS_PHF;
    kT_f <<<235, 256, 0, stream>>>(W1, W1t);
    kH_f <<<NB * KSEG, 192, 0, stream>>>(sf, W1t, ph);
    k1b_f<<<66, 512, 0, stream>>>(ph, W2, b1, b2, q_t);
    k2_f <<<NB * QSEG, 256, 0, stream>>>(sf, q_t, attn, md);
    k3_f <<<NB * NJ, 256, 0, stream>>>(attn, md);
    k4_f <<<NB * KSEG, 192, 0, stream>>>(sf, attn, ph);
    k5_f <<<1572, 512, 0, stream>>>(ph, out);
  }
}

// Round 11
// 440.830 us; speedup vs baseline: 1.1765x; 1.0503x over previous
//
#include <hip/hip_runtime.h>
#include <cstdint>
#include <cstddef>

#define NB 256
#define NS 2500
#define NJ 24
#define DF 131

#define QSEG 4           // n segments for k2m (md interface)
#define TSEG 640         // k2m/kW TILE-partition segment size: 40 tiles of 16

#define KP 2528          // padded K (c) for MFMA, 79 steps of 32
#define XNROWS 2512      // 157 tiles of 16
#define LP 160           // padded l for score MFMA (5 k-steps of 32)
#define XRS 130          // kP2 transposed-LDS row stride in shorts (65 dwords, odd)

using short8 = __attribute__((ext_vector_type(8))) short;
using f32x4  = __attribute__((ext_vector_type(4))) float;

// ---- FULL-path ws byte offsets ----
#define F_XT   0ull                        // [NB][144][KP] bf16
#define F_XN   186384384ull                // [NB][XNROWS][LP] bf16
#define F_W1B  392167424ull                // [32][KP] bf16
#define F_QBF  392329216ull                // [NB][32][LP] bf16
#define F_H    394950656ull                // [NB][NJ][DF] f32
#define F_MD   398170112ull                // [NB][QSEG][48] f32
#define F_P    398366720ull                // [NB][NJ][KP] bf16
#define WS_FULL 429430784ull

__device__ __forceinline__ unsigned short f2bf(float x) {
  union { float f; unsigned u; } v; v.f = x;
  unsigned r = v.u + 0x7fffu + ((v.u >> 16) & 1u);   // RNE
  return (unsigned short)(r >> 16);
}
__device__ __forceinline__ float bf2f(unsigned us) {
  union { unsigned u; float f; } v; v.u = us << 16;
  return v.f;
}
__device__ __forceinline__ f32x4 mfma16(short8 a, short8 b, f32x4 c) {
  return __builtin_amdgcn_mfma_f32_16x16x32_bf16(a, b, c, 0, 0, 0);
}

// W1 [24][2500] f32 -> W1b [32][KP] bf16, zero-padded
__global__ __launch_bounds__(256) void kT2(const float* __restrict__ W1,
                                           unsigned short* __restrict__ W1b) {
  int dwi = blockIdx.x * 256 + threadIdx.x;
  if (dwi >= 32 * (KP / 2)) return;
  int row = dwi / (KP / 2);
  int kk = (dwi - row * (KP / 2)) * 2;
  unsigned lo = (row < NJ && kk     < NS) ? f2bf(W1[row * NS + kk])     : 0;
  unsigned hi = (row < NJ && kk + 1 < NS) ? f2bf(W1[row * NS + kk + 1]) : 0;
  ((unsigned*)W1b)[dwi] = lo | (hi << 16);
}

// X f32 [b][c][l] -> Xt bf16 [b][l][c-pad] + Xn bf16 [b][c][l-pad].
// Phase 1: coalesced reads, TRANSPOSED LDS writes (u16 banks (lane+r/2)%32: 2-way
// free), Xn written DIRECTLY from registers (contiguous u16, incl. zero-pad).
// Phase 2a: consecutive-dword LDS reads (free) + coalesced dword Xt stores.
__global__ __launch_bounds__(256) void kP2(const float* __restrict__ sf,
                                           unsigned short* __restrict__ Xt,
                                           unsigned short* __restrict__ Xn) {
  __shared__ unsigned short xs[131 * XRS];         // xs[l][c], 34060 B
  int b = blockIdx.x / 20;
  int chunk = blockIdx.x - 20 * b;
  int c0 = chunk * 128;
  int w = threadIdx.x >> 6, lane = threadIdx.x & 63;
  const float* xb = sf + (size_t)b * (NS * DF);
  unsigned short* xnb = Xn + (size_t)b * (XNROWS * LP);

#pragma unroll 4
  for (int i = 0; i < 32; ++i) {
    int r = w * 32 + i;
    int c = c0 + r;
    bool vc = c < NS;
    const float* g = xb + (size_t)c * DF;
    float v0 = vc ? g[lane] : 0.f;                 // coalesced
    float v1 = vc ? g[64 + lane] : 0.f;
    float v2 = (vc && lane < 3) ? g[128 + lane] : 0.f;
    unsigned short b0 = f2bf(v0), b1 = f2bf(v1), b2 = f2bf(v2);
    xs[lane * XRS + r] = b0;                       // transposed: xs[l][r]
    xs[(64 + lane) * XRS + r] = b1;
    if (lane < 3) xs[(128 + lane) * XRS + r] = b2;
    if (c < XNROWS) {                              // Xn direct (contiguous u16)
      xnb[(size_t)c * LP + lane] = b0;
      xnb[(size_t)c * LP + 64 + lane] = b1;
      if (lane < 32)
        xnb[(size_t)c * LP + 128 + lane] = (lane < 3) ? b2 : (unsigned short)0;
    }
  }
  __syncthreads();

  // phase 2a: Xt[l][cc,cc+1] — 1 ds_read_b32 (consecutive) + 1 dword store per iter
  int cc = c0 + 2 * lane;
  if (cc < KP) {
    unsigned short* xtb = Xt + (size_t)b * (144 * KP);
    const unsigned* xsd = (const unsigned*)xs;
#pragma unroll 4
    for (int l = w; l < DF; l += 4) {
      unsigned v = xsd[l * (XRS / 2) + lane];      // dword idx 65*l + lane
      *(unsigned*)(xtb + (size_t)l * KP + cc) = v;
    }
  }
}

// h[b][j][l] = (W1 @ X_b) via MFMA
__global__ __launch_bounds__(384) void kH(const unsigned short* __restrict__ Xt,
                                          const unsigned short* __restrict__ W1b,
                                          float* __restrict__ h) {
  int bi = blockIdx.x;
  int b = bi / 3, ng = bi - 3 * b;
  int wid = threadIdx.x >> 6, lane = threadIdx.x & 63;
  int m = wid / 3, nt = wid - 3 * m;
  int col0 = ng * 48 + nt * 16;
  int lr = lane & 15, lg = lane >> 4;

  const unsigned short* ap = W1b + (size_t)(m * 16 + lr) * KP + lg * 8;
  const unsigned short* bp = Xt + (size_t)b * (144 * KP) + (size_t)(col0 + lr) * KP + lg * 8;

  f32x4 acc = {0.f, 0.f, 0.f, 0.f};
#pragma unroll 4
  for (int ks = 0; ks < KP / 32; ++ks) {
    short8 av = *(const short8*)(ap + ks * 32);
    short8 bv = *(const short8*)(bp + ks * 32);
    acc = mfma16(av, bv, acc);
  }
  int lcol = col0 + lr;
  if (lcol < DF) {
    int jb = m * 16 + lg * 4;
#pragma unroll
    for (int r = 0; r < 4; ++r) {
      int j = jb + r;
      if (j < NJ) h[(size_t)b * (NJ * DF) + (size_t)j * DF + lcol] = acc[r];
    }
  }
}

// relu(h+b1) -> q = W2@. + b2 -> qbf bf16 [b][32][LP]
__global__ __launch_bounds__(512) void k1b(const float* __restrict__ h,
                                           const float* __restrict__ W2,
                                           const float* __restrict__ b1v,
                                           const float* __restrict__ b2v,
                                           unsigned short* __restrict__ qbf) {
  int flat = blockIdx.x * 512 + threadIdx.x;      // NB*LP threads
  if (flat >= NB * LP) return;
  int l = flat % LP;
  int b = flat / LP;
  unsigned short* qp = qbf + (size_t)b * (32 * LP) + l;
  if (l >= DF) {
#pragma unroll
    for (int j = 0; j < 32; ++j) qp[j * LP] = 0;
    return;
  }
  const float* p0 = h + (size_t)b * (NJ * DF) + l;
  float hv[NJ];
#pragma unroll
  for (int o = 0; o < NJ; ++o) hv[o] = fmaxf(b1v[o] + p0[o * DF], 0.f);
  float q[NJ];
  for (int o = 0; o < NJ; ++o) {
    float sv = b2v[o];
#pragma unroll
    for (int i = 0; i < NJ; ++i) sv = fmaf(W2[o * NJ + i], hv[i], sv);
    q[o] = sv;
  }
#pragma unroll
  for (int j = 0; j < NJ; ++j) qp[j * LP] = f2bf(q[j]);
#pragma unroll
  for (int j = NJ; j < 32; ++j) qp[j * LP] = 0;
}

// MFMA scores from Xn (bf16, 16B-aligned short8 loads), two-pass-in-registers:
// P = exp(S - m_seg) bf16 + per-seg (m,d). n partition BY TILES: seg = n/640.
__global__ __launch_bounds__(512) void k2m(const unsigned short* __restrict__ Xn,
                                           const unsigned short* __restrict__ qbf,
                                           unsigned short* __restrict__ P,
                                           float* __restrict__ md) {
  __shared__ float wm[8][24];
  __shared__ float wd[8][24];
  int b = blockIdx.x >> 2, seg = blockIdx.x & 3;
  int w = threadIdx.x >> 6, lane = threadIdx.x & 63;
  int lr = lane & 15, lg = lane >> 4;

  const unsigned short* qb = qbf + (size_t)b * (32 * LP);
  short8 aq0[5], aq1[5];
#pragma unroll
  for (int ks = 0; ks < 5; ++ks) {
    aq0[ks] = *(const short8*)(qb + (size_t)lr * LP + ks * 32 + lg * 8);
    aq1[ks] = *(const short8*)(qb + (size_t)(16 + lr) * LP + ks * 32 + lg * 8);
  }
  const unsigned short* xb = Xn + (size_t)b * (XNROWS * LP);
  int ntl = (seg < 3) ? 40 : 37;

  f32x4 s0[5], s1[5];
  float m8[8];
#pragma unroll
  for (int r = 0; r < 8; ++r) m8[r] = -1e30f;

#pragma unroll
  for (int i = 0; i < 5; ++i) {
    s0[i] = (f32x4){0.f, 0.f, 0.f, 0.f};
    s1[i] = (f32x4){0.f, 0.f, 0.f, 0.f};
    int ti = w + 8 * i;
    if (ti < ntl) {
      int n = (seg * 40 + ti) * 16 + lr;
      const unsigned short* bp = xb + (size_t)n * LP + lg * 8;
      short8 bx[5];
#pragma unroll
      for (int ks = 0; ks < 5; ++ks) bx[ks] = *(const short8*)(bp + ks * 32);
      f32x4 a0 = {0.f, 0.f, 0.f, 0.f}, a1 = {0.f, 0.f, 0.f, 0.f};
#pragma unroll
      for (int ks = 0; ks < 5; ++ks) {
        a0 = mfma16(aq0[ks], bx[ks], a0);
        a1 = mfma16(aq1[ks], bx[ks], a1);
      }
      s0[i] = a0; s1[i] = a1;
#pragma unroll
      for (int r = 0; r < 4; ++r) {
        m8[r]     = fmaxf(m8[r],     a0[r]);
        m8[4 + r] = fmaxf(m8[4 + r], a1[r]);
      }
    }
  }
  // max over 16 n-lanes
#pragma unroll
  for (int r = 0; r < 8; ++r)
#pragma unroll
    for (int off = 1; off < 16; off <<= 1)
      m8[r] = fmaxf(m8[r], __shfl_xor(m8[r], off));
  if (lr == 0) {
#pragma unroll
    for (int r = 0; r < 4; ++r) {
      wm[w][lg * 4 + r] = m8[r];
      if (lg < 2) wm[w][16 + lg * 4 + r] = m8[4 + r];
    }
  }
  __syncthreads();
  float mseg[8];
#pragma unroll
  for (int r = 0; r < 4; ++r) {
    float m0 = wm[0][lg * 4 + r];
#pragma unroll
    for (int wv = 1; wv < 8; ++wv) m0 = fmaxf(m0, wm[wv][lg * 4 + r]);
    mseg[r] = m0;
    int j1 = 16 + (lg & 1) * 4 + r;
    float m1 = wm[0][j1];
#pragma unroll
    for (int wv = 1; wv < 8; ++wv) m1 = fmaxf(m1, wm[wv][j1]);
    mseg[4 + r] = m1;
  }
  float d8[8];
#pragma unroll
  for (int r = 0; r < 8; ++r) d8[r] = 0.f;
#pragma unroll
  for (int i = 0; i < 5; ++i) {
    int ti = w + 8 * i;
    if (ti < ntl) {
      int n = (seg * 40 + ti) * 16 + lr;
      bool valid = n < NS;
#pragma unroll
      for (int r = 0; r < 4; ++r) {
        float p0 = __expf(s0[i][r] - mseg[r]);
        float p1 = __expf(s1[i][r] - mseg[4 + r]);
        if (valid) {
          P[((size_t)b * NJ + lg * 4 + r) * KP + n] = f2bf(p0);
          d8[r] += p0;
          if (lg < 2) {
            P[((size_t)b * NJ + 16 + lg * 4 + r) * KP + n] = f2bf(p1);
            d8[4 + r] += p1;
          }
        }
      }
    }
  }
#pragma unroll
  for (int r = 0; r < 8; ++r)
#pragma unroll
    for (int off = 1; off < 16; off <<= 1)
      d8[r] += __shfl_xor(d8[r], off);
  if (lr == 0) {
#pragma unroll
    for (int r = 0; r < 4; ++r) {
      wd[w][lg * 4 + r] = d8[r];
      if (lg < 2) wd[w][16 + lg * 4 + r] = d8[4 + r];
    }
  }
  __syncthreads();
  if (threadIdx.x < NJ) {
    int j = threadIdx.x;
    float m = wm[0][j], d = 0.f;
#pragma unroll
    for (int wv = 1; wv < 8; ++wv) m = fmaxf(m, wm[wv][j]);
#pragma unroll
    for (int wv = 0; wv < 8; ++wv) d += wd[wv][j];
    float* mp = md + ((size_t)b * QSEG + seg) * 48;
    mp[j] = m;
    mp[24 + j] = d;
  }
}

// combine md; write attention f32 (required output) + normalize P bf16 in place.
// Segment of n is the TILE partition n/TSEG (640).
__global__ __launch_bounds__(256) void kW(unsigned short* __restrict__ P,
                                          const float* __restrict__ md,
                                          float* __restrict__ attn) {
  int bj = blockIdx.x;
  int b = bj / NJ, j = bj - b * NJ;
  const float* mp = md + (size_t)b * (QSEG * 48);
  float ms[QSEG];
  float m = -1e30f;
#pragma unroll
  for (int s = 0; s < QSEG; ++s) { ms[s] = mp[s * 48 + j]; m = fmaxf(m, ms[s]); }
  float d = 0.f;
#pragma unroll
  for (int s = 0; s < QSEG; ++s) d += mp[s * 48 + 24 + j] * __expf(ms[s] - m);
  float rinv = 1.f / d;
  float cs[QSEG];
#pragma unroll
  for (int s = 0; s < QSEG; ++s) cs[s] = __expf(ms[s] - m) * rinv;

  unsigned* prow = (unsigned*)(P + (size_t)bj * KP);
  float2* arow = (float2*)(attn + (size_t)bj * NS);
  for (int i = threadIdx.x; i < NS / 2; i += 256) {
    unsigned pk = prow[i];
    int n0 = 2 * i;
    float p0 = bf2f(pk & 0xffffu) * cs[n0 / TSEG];
    float p1 = bf2f(pk >> 16) * cs[(n0 + 1) / TSEG];
    arow[i] = make_float2(p0, p1);
    prow[i] = (unsigned)f2bf(p0) | ((unsigned)f2bf(p1) << 16);
  }
  if (threadIdx.x < (KP - NS) / 2) prow[NS / 2 + threadIdx.x] = 0;   // k-pad zeros
}

// out[b][j][l] = attn_b @ X_b via MFMA (A rows clamped; rows>=24 feed discarded C rows)
__global__ __launch_bounds__(384) void k4(const unsigned short* __restrict__ Xt,
                                          const unsigned short* __restrict__ abf,
                                          float* __restrict__ out) {
  int bi = blockIdx.x;
  int b = bi / 3, ng = bi - 3 * b;
  int wid = threadIdx.x >> 6, lane = threadIdx.x & 63;
  int m = wid / 3, nt = wid - 3 * m;
  int col0 = ng * 48 + nt * 16;
  int lr = lane & 15, lg = lane >> 4;

  int arow = m * 16 + lr; if (arow > 23) arow = 23;
  const unsigned short* ap = abf + ((size_t)b * NJ + arow) * KP + lg * 8;
  const unsigned short* bp = Xt + (size_t)b * (144 * KP) + (size_t)(col0 + lr) * KP + lg * 8;

  f32x4 acc = {0.f, 0.f, 0.f, 0.f};
#pragma unroll 4
  for (int ks = 0; ks < KP / 32; ++ks) {
    short8 av = *(const short8*)(ap + ks * 32);
    short8 bv = *(const short8*)(bp + ks * 32);
    acc = mfma16(av, bv, acc);
  }
  int lcol = col0 + lr;
  if (lcol < DF) {
    int jb = m * 16 + lg * 4;
#pragma unroll
    for (int r = 0; r < 4; ++r) {
      int j = jb + r;
      if (j < NJ) out[(size_t)b * (NJ * DF) + (size_t)j * DF + lcol] = acc[r];
    }
  }
}

// =============== FP32 fallback (round-3, known-pass) ===============
#define KSEG 8
#define CSEG 313
#define SEGN 625
#define TN 64
#define LDP 132
#define WS_W1T 0u
#define WS_QTF 60000u
#define WS_MDF (WS_QTF + 804864u)
#define WS_PHF (WS_MDF + (unsigned)(NB * QSEG * 48))
#define SEGSTRIDE ((size_t)NB * NJ * DF)

__global__ __launch_bounds__(256) void kT_f(const float* __restrict__ W1,
                                            float* __restrict__ W1t) {
  int i = blockIdx.x * 256 + threadIdx.x;
  if (i >= NJ * NS) return;
  int o = i / NS, c = i - o * NS;
  W1t[c * NJ + o] = W1[i];
}

__global__ __launch_bounds__(192) void kH_f(const float* __restrict__ sf,
                                            const float* __restrict__ W1t,
                                            float* __restrict__ ph) {
  int b = blockIdx.x >> 3;
  int s = blockIdx.x & 7;
  int l = threadIdx.x;
  int c0 = s * CSEG;
  int cnt = NS - c0; if (cnt > CSEG) cnt = CSEG;
  const float* xp = sf + (size_t)b * (NS * DF) + (size_t)c0 * DF;
  const float* wp = W1t + (size_t)c0 * NJ;
  float acc[NJ];
#pragma unroll
  for (int o = 0; o < NJ; ++o) acc[o] = 0.f;
  if (l < DF) {
#pragma unroll 2
    for (int c = 0; c < cnt; ++c) {
      float xv = xp[(size_t)c * DF + l];
#pragma unroll
      for (int o = 0; o < NJ; ++o) acc[o] = fmaf(wp[c * NJ + o], xv, acc[o]);
    }
    float* pp = ph + (size_t)(s * NB + b) * (NJ * DF) + l;
#pragma unroll
    for (int o = 0; o < NJ; ++o) pp[o * DF] = acc[o];
  }
}

__global__ __launch_bounds__(512) void k1b_f(const float* __restrict__ ph,
                                             const float* __restrict__ W2,
                                             const float* __restrict__ b1v,
                                             const float* __restrict__ b2v,
                                             float* __restrict__ q_t) {
  int flat = blockIdx.x * 512 + threadIdx.x;
  if (flat >= NB * DF) return;
  int l = flat % DF;
  int b = flat / DF;
  const float* p0 = ph + (size_t)(b * NJ) * DF + l;
  float hv[NJ];
#pragma unroll
  for (int o = 0; o < NJ; ++o) hv[o] = b1v[o];
  for (int s = 0; s < KSEG; ++s) {
#pragma unroll
    for (int o = 0; o < NJ; ++o) hv[o] += p0[s * SEGSTRIDE + o * DF];
  }
#pragma unroll
  for (int o = 0; o < NJ; ++o) hv[o] = fmaxf(hv[o], 0.f);
  float q[NJ];
  for (int o = 0; o < NJ; ++o) {
    float sv = b2v[o];
#pragma unroll
    for (int i = 0; i < NJ; ++i) sv = fmaf(W2[o * NJ + i], hv[i], sv);
    q[o] = sv;
  }
  float4* qp = (float4*)(q_t + (size_t)flat * NJ);
#pragma unroll
  for (int v = 0; v < 6; ++v)
    qp[v] = make_float4(q[4 * v], q[4 * v + 1], q[4 * v + 2], q[4 * v + 3]);
}

__global__ __launch_bounds__(256) void k2_f(const float* __restrict__ sf,
                                            const float* __restrict__ q_t,
                                            float* __restrict__ raw,
                                            float* __restrict__ md) {
  __shared__ __align__(16) float xs[TN * LDP];
  int b = blockIdx.x >> 2;
  int s = blockIdx.x & 3;
  int tid = threadIdx.x;
  int wid = tid >> 6, lane = tid & 63;
  int jq = __builtin_amdgcn_readfirstlane(wid);

  const float* sft = sf + (size_t)b * (NS * DF) + (size_t)(s * SEGN) * DF;
  const float* qb = q_t + (size_t)b * (DF * NJ) + jq * 6;
  float* rawb = raw + (size_t)b * (NJ * NS) + (size_t)(s * SEGN);

  float m6[6], d6[6];
#pragma unroll
  for (int i = 0; i < 6; ++i) { m6[i] = -1e30f; d6[i] = 0.f; }

  const int NT = (SEGN + TN - 1) / TN;
  for (int t = 0; t < NT; ++t) {
    int n0 = t * TN;
    int nmax = SEGN - n0; if (nmax > TN) nmax = TN;
    __syncthreads();
#pragma unroll
    for (int rr = 0; rr < 16; ++rr) {
      int r = wid * 16 + rr;
      if (r < nmax) {
        const float* g = sft + (size_t)(n0 + r) * DF;
        float* d = xs + r * LDP;
        d[lane] = g[lane];
        d[64 + lane] = g[64 + lane];
        if (lane < 3) d[128 + lane] = g[128 + lane];
      }
    }
    __syncthreads();
    if (lane < nmax) {
      const float* xrow = xs + lane * LDP;
      float sa[6];
#pragma unroll
      for (int i = 0; i < 6; ++i) sa[i] = 0.f;
      for (int l4 = 0; l4 < 32; ++l4) {
        float4 xv = *(const float4*)(xrow + 4 * l4);
        const float* q4 = qb + (4 * l4) * NJ;
#pragma unroll
        for (int i = 0; i < 6; ++i) sa[i] = fmaf(q4[i], xv.x, sa[i]);
#pragma unroll
        for (int i = 0; i < 6; ++i) sa[i] = fmaf(q4[NJ + i], xv.y, sa[i]);
#pragma unroll
        for (int i = 0; i < 6; ++i) sa[i] = fmaf(q4[2 * NJ + i], xv.z, sa[i]);
#pragma unroll
        for (int i = 0; i < 6; ++i) sa[i] = fmaf(q4[3 * NJ + i], xv.w, sa[i]);
      }
#pragma unroll
      for (int l = 128; l < DF; ++l) {
        float xv = xrow[l];
#pragma unroll
        for (int i = 0; i < 6; ++i) sa[i] = fmaf(qb[l * NJ + i], xv, sa[i]);
      }
      int nr = n0 + lane;
#pragma unroll
      for (int i = 0; i < 6; ++i) {
        rawb[(size_t)(jq * 6 + i) * NS + nr] = sa[i];
        float mn = fmaxf(m6[i], sa[i]);
        d6[i] = d6[i] * __expf(m6[i] - mn) + __expf(sa[i] - mn);
        m6[i] = mn;
      }
    }
  }
#pragma unroll
  for (int i = 0; i < 6; ++i) {
    float m = m6[i], d = d6[i];
    for (int off = 32; off > 0; off >>= 1) {
      float mo = __shfl_xor(m, off);
      float dd = __shfl_xor(d, off);
      float nm = fmaxf(m, mo);
      d = d * __expf(m - nm) + dd * __expf(mo - nm);
      m = nm;
    }
    m6[i] = m; d6[i] = d;
  }
  if (lane == 0) {
    float* mp = md + ((size_t)b * QSEG + s) * 48;
#pragma unroll
    for (int i = 0; i < 6; ++i) {
      mp[jq * 6 + i] = m6[i];
      mp[24 + jq * 6 + i] = d6[i];
    }
  }
}

__global__ __launch_bounds__(256) void k3_f(float* __restrict__ attn,
                                            const float* __restrict__ md) {
  int bj = blockIdx.x;
  int b = bj / NJ;
  int j = bj - b * NJ;
  const float* mp = md + (size_t)b * (QSEG * 48);
  float m = -1e30f, d = 0.f;
#pragma unroll
  for (int s = 0; s < QSEG; ++s) {
    float ms = mp[s * 48 + j], ds = mp[s * 48 + 24 + j];
    float nm = fmaxf(m, ms);
    d = d * __expf(m - nm) + ds * __expf(ms - nm);
    m = nm;
  }
  float r = 1.f / d;
  float* p = attn + (size_t)bj * NS;
  for (int n = threadIdx.x; n < NS; n += 256)
    p[n] = __expf(p[n] - m) * r;
}

__global__ __launch_bounds__(192) void k4_f(const float* __restrict__ sf,
                                            const float* __restrict__ attn,
                                            float* __restrict__ po) {
  int b = blockIdx.x >> 3;
  int s = blockIdx.x & 7;
  int l = threadIdx.x;
  int n0 = s * CSEG;
  int cnt = NS - n0; if (cnt > CSEG) cnt = CSEG;
  const float* xp = sf + (size_t)b * (NS * DF) + (size_t)n0 * DF;
  const float* ap = attn + (size_t)b * (NJ * NS) + n0;
  float acc[NJ];
#pragma unroll
  for (int o = 0; o < NJ; ++o) acc[o] = 0.f;
  if (l < DF) {
#pragma unroll 2
    for (int n = 0; n < cnt; ++n) {
      float xv = xp[(size_t)n * DF + l];
#pragma unroll
      for (int o = 0; o < NJ; ++o) acc[o] = fmaf(ap[(size_t)o * NS + n], xv, acc[o]);
    }
    float* pp = po + (size_t)(s * NB + b) * (NJ * DF) + l;
#pragma unroll
    for (int o = 0; o < NJ; ++o) pp[o * DF] = acc[o];
  }
}

__global__ __launch_bounds__(512) void k5_f(const float* __restrict__ po,
                                            float* __restrict__ out) {
  int i = blockIdx.x * 512 + threadIdx.x;
  float v = 0.f;
#pragma unroll
  for (int s = 0; s < KSEG; ++s) v += po[s * SEGSTRIDE + i];
  out[i] = v;
}

extern "C" void kernel_launch(void* const* d_in, const int* in_sizes, int n_in,
                              void* d_out, int out_size, void* d_ws, size_t ws_size,
                              hipStream_t stream) {
  const float* sf = (const float*)d_in[0];
  const float* W1 = (const float*)d_in[1];
  const float* b1 = (const float*)d_in[2];
  const float* W2 = (const float*)d_in[3];
  const float* b2 = (const float*)d_in[4];
  float* out = (float*)d_out;
  float* attn = out + (size_t)NB * NJ * DF;

  if (ws_size >= WS_FULL) {
    unsigned short* Xt  = (unsigned short*)((char*)d_ws + F_XT);
    unsigned short* Xn  = (unsigned short*)((char*)d_ws + F_XN);
    unsigned short* W1b = (unsigned short*)((char*)d_ws + F_W1B);
    unsigned short* qbf = (unsigned short*)((char*)d_ws + F_QBF);
    float* hbuf = (float*)((char*)d_ws + F_H);
    float* md   = (float*)((char*)d_ws + F_MD);
    unsigned short* P   = (unsigned short*)((char*)d_ws + F_P);

    kT2<<<158, 256, 0, stream>>>(W1, W1b);
    kP2<<<NB * 20, 256, 0, stream>>>(sf, Xt, Xn);
    kH <<<NB * 3, 384, 0, stream>>>(Xt, W1b, hbuf);
    k1b<<<80, 512, 0, stream>>>(hbuf, W2, b1, b2, qbf);
    k2m<<<NB * QSEG, 512, 0, stream>>>(Xn, qbf, P, md);
    kW <<<NB * NJ, 256, 0, stream>>>(P, md, attn);
    k4 <<<NB * 3, 384, 0, stream>>>(Xt, P, out);
  } else {
    float* ws = (float*)d_ws;
    float* W1t = ws + WS_W1T;
    float* q_t = ws + WS_QTF;
    float* md  = ws + WS_MDF;
    float* ph  = ws + WS_PHF;
    kT_f <<<235, 256, 0, stream>>>(W1, W1t);
    kH_f <<<NB * KSEG, 192, 0, stream>>>(sf, W1t, ph);
    k1b_f<<<66, 512, 0, stream>>>(ph, W2, b1, b2, q_t);
    k2_f <<<NB * QSEG, 256, 0, stream>>>(sf, q_t, attn, md);
    k3_f <<<NB * NJ, 256, 0, stream>>>(attn, md);
    k4_f <<<NB * KSEG, 192, 0, stream>>>(sf, attn, ph);
    k5_f <<<1572, 512, 0, stream>>>(ph, out);
  }
}